// Round 1
// baseline (129.557 us; speedup 1.0000x reference)
//
#include <hip/hip_runtime.h>
#include <hip/hip_bf16.h>

#pragma clang fp contract(off)

#define NEGV (-1000000000.0f)

__device__ __forceinline__ float i2f(int x) { return __int_as_float(x); }
__device__ __forceinline__ int f2i(float x) { return __float_as_int(x); }

// DPP wave64 reductions (VALU pipe; no LDS / ds_bpermute traffic).
// max: old = own value (identity under max), bound_ctrl=false.
#define DPP_MAX_STEP(x, ctrl, rm, bm)                                          \
  x = fmaxf(x, i2f(__builtin_amdgcn_update_dpp(f2i(x), f2i(x), ctrl, rm, bm, false)))
// add: bound_ctrl=true -> invalid source lanes contribute 0 (no double count);
// dest lanes masked off by row_mask keep old (their own x) but are never
// sources for the remaining steps that feed lane 63.
#define DPP_ADD_STEP(x, ctrl, rm, bm)                                          \
  x = x + i2f(__builtin_amdgcn_update_dpp(f2i(x), f2i(x), ctrl, rm, bm, true))

__device__ __forceinline__ float wave_red_max(float x) {
  DPP_MAX_STEP(x, 0x111, 0xf, 0xf);  // row_shr:1
  DPP_MAX_STEP(x, 0x112, 0xf, 0xf);  // row_shr:2
  DPP_MAX_STEP(x, 0x114, 0xf, 0xf);  // row_shr:4
  DPP_MAX_STEP(x, 0x118, 0xf, 0xf);  // row_shr:8
  DPP_MAX_STEP(x, 0x142, 0xa, 0xf);  // row_bcast:15 -> rows 1,3
  DPP_MAX_STEP(x, 0x143, 0xc, 0xf);  // row_bcast:31 -> rows 2,3
  return i2f(__builtin_amdgcn_readlane(f2i(x), 63));
}

__device__ __forceinline__ float wave_red_add(float x) {
  DPP_ADD_STEP(x, 0x111, 0xf, 0xf);
  DPP_ADD_STEP(x, 0x112, 0xf, 0xf);
  DPP_ADD_STEP(x, 0x114, 0xf, 0xf);
  DPP_ADD_STEP(x, 0x118, 0xf, 0xf);
  DPP_ADD_STEP(x, 0x142, 0xa, 0xf);
  DPP_ADD_STEP(x, 0x143, 0xc, 0xf);
  return i2f(__builtin_amdgcn_readlane(f2i(x), 63));
}

__device__ __forceinline__ float readlane_f(float v, int lane) {
  return i2f(__builtin_amdgcn_readlane(f2i(v), lane));
}

// ---------------------------------------------------------------------------
// Kernel 1: per-slot tables from transformer_class_probs (128 x 134).
// cls_pred[s] = argmax_j probs[s][0..132] (first index on ties)
// det_flag[s] = max >= 0.7 ; det_idx[s] = cumsum(det)-1 ; num_det = total
// ---------------------------------------------------------------------------
__global__ __launch_bounds__(128) void slot_kernel(
    const float* __restrict__ probs, float* __restrict__ cls_pred,
    int* __restrict__ det_idx, int* __restrict__ det_flag,
    int* __restrict__ num_det) {
  __shared__ int flags[128];
  int t = threadIdx.x;  // 0..127, one slot per thread
  const float* row = probs + t * 134;
  float best = -1.0f;
  int arg = 0;
  for (int j = 0; j < 133; ++j) {
    float p = row[j];
    if (p > best) { best = p; arg = j; }  // strict > keeps first-max index
  }
  int det = (best >= 0.7f) ? 1 : 0;
  flags[t] = det;
  __syncthreads();
  int c = 0;
  for (int j = 0; j <= t; ++j) c += flags[j];
  cls_pred[t] = (float)arg;
  det_idx[t] = c - 1;
  det_flag[t] = det;
  if (t == 127) *num_det = c;
}

// ---------------------------------------------------------------------------
// Kernel 2: one wave per 4x4 output tile. Lanes hold 2 channels each
// (128 ch / 64 lanes). Tile (ty,tx) needs input texels (ty,tx),(ty,tx1),
// (ty1,tx),(ty1,tx1) only, since the resize scale is exactly 1/4.
// ---------------------------------------------------------------------------
__global__ __launch_bounds__(256) void post_kernel(
    const float* __restrict__ logits, const float* __restrict__ cls_pred,
    const int* __restrict__ det_idx, const int* __restrict__ det_flag,
    const int* __restrict__ num_det_p, float* __restrict__ out) {
#pragma clang fp contract(off)
  const int NT = 161 * 161;      // tiles
  const int NP = 641 * 641;      // pixels per output map
  int wave = threadIdx.x >> 6;
  int lane = threadIdx.x & 63;
  int t = blockIdx.x * 4 + wave;
  if (t >= NT) return;
  int ty = t / 161;
  int tx = t - ty * 161;
  int ty1 = min(ty + 1, 160);
  int tx1 = min(tx + 1, 160);
  int ch = lane * 2;

  const float* b = logits;
  float2 a00 = *(const float2*)(b + ((ty  * 161 + tx ) * 128 + ch));
  float2 a01 = *(const float2*)(b + ((ty  * 161 + tx1) * 128 + ch));
  float2 a10 = *(const float2*)(b + ((ty1 * 161 + tx ) * 128 + ch));
  float2 a11 = *(const float2*)(b + ((ty1 * 161 + tx1) * 128 + ch));

  int2 dfl  = *(const int2*)(det_flag + ch);
  float2 cls = *(const float2*)(cls_pred + ch);
  int2 didx = *(const int2*)(det_idx + ch);
  int ndet = *num_det_p;
  bool all_det = (ndet == 128);
  bool has_det = (ndet > 0);

  float o0 = 0.f, o1 = 0.f, o2 = 0.f, o3 = 0.f;

#pragma unroll
  for (int dy = 0; dy < 4; ++dy) {
    float wy = 0.25f * (float)dy;
    float iwy = 1.0f - wy;
    // y-interp first (matches reference op order for fp32 bit-exactness)
    float r0x = a00.x * iwy + a10.x * wy;
    float r0y = a00.y * iwy + a10.y * wy;
    float r1x = a01.x * iwy + a11.x * wy;
    float r1y = a01.y * iwy + a11.y * wy;
#pragma unroll
    for (int dx = 0; dx < 4; ++dx) {
      float wx = 0.25f * (float)dx;
      float iwx = 1.0f - wx;
      float vx = r0x * iwx + r1x * wx;
      float vy = r0y * iwx + r1y * wx;

      float rawmax = wave_red_max(fmaxf(vx, vy));
      float mx, my, detmax, detpix;
      if (all_det) {
        mx = vx; my = vy; detmax = rawmax; detpix = 1.0f;
      } else {
        mx = dfl.x ? vx : NEGV;
        my = dfl.y ? vy : NEGV;
        detmax = wave_red_max(fmaxf(mx, my));
        detpix = (rawmax == detmax) ? 1.0f : 0.0f;
      }

      // first-index argmax over masked values (jnp tie-break semantics)
      unsigned long long bx = __ballot(mx == detmax);
      unsigned long long by = __ballot(my == detmax);
      int slot = 1 << 30;
      if (bx) slot = 2 * __builtin_ctzll(bx);
      if (by) slot = min(slot, 2 * __builtin_ctzll(by) + 1);

      float ex = expf(mx - detmax);
      float ey = expf(my - detmax);
      float S = wave_red_add(ex + ey);
      float conf = 1.0f / S;  // max softmax == exp(0)/S
      float confreg = (conf > 0.4f) ? detpix : 0.0f;

      int sl = slot >> 1;
      float sem = (slot & 1) ? readlane_f(cls.y, sl) : readlane_f(cls.x, sl);
      int mid = ((slot & 1) ? __builtin_amdgcn_readlane(didx.y, sl)
                            : __builtin_amdgcn_readlane(didx.x, sl)) + 1;
      float thing = (sem < 80.0f) ? confreg : 0.0f;
      float stuff = (sem >= 80.0f) ? confreg : 0.0f;
      // THING_STUFF_IDS == arange(133): semantic = round(sem) == sem exactly
      float semf = sem;
      if (!has_det) { mid = 1; semf = 0.0f; thing = 0.0f; stuff = 0.0f; }

      int pix = dy * 4 + dx;
      if (lane == pix) { o0 = (float)mid; o1 = semf; o2 = thing; o3 = stuff; }
    }
  }

  if (lane < 16) {
    int dy = lane >> 2, dx = lane & 3;
    int y = 4 * ty + dy;
    int x = 4 * tx + dx;
    if (y < 641 && x < 641) {
      int idx = y * 641 + x;
      out[idx] = o0;
      out[NP + idx] = o1;
      out[2 * NP + idx] = o2;
      out[3 * NP + idx] = o3;
    }
  }
}

extern "C" void kernel_launch(void* const* d_in, const int* in_sizes, int n_in,
                              void* d_out, int out_size, void* d_ws,
                              size_t ws_size, hipStream_t stream) {
  const float* logits = (const float*)d_in[0];  // (161,161,128) f32
  const float* probs = (const float*)d_in[1];   // (128,134) f32
  float* out = (float*)d_out;                   // 4 x 641*641, written as f32

  float* ws_f = (float*)d_ws;
  float* cls_pred = ws_f;                // 128 floats
  int* det_idx = (int*)(ws_f + 128);     // 128 ints
  int* det_flag = (int*)(ws_f + 256);    // 128 ints
  int* num_det = (int*)(ws_f + 384);     // 1 int

  slot_kernel<<<1, 128, 0, stream>>>(probs, cls_pred, det_idx, det_flag,
                                     num_det);

  const int NT = 161 * 161;          // 4x4 output tiles
  int blocks = (NT + 3) / 4;         // 4 waves (tiles) per 256-thread block
  post_kernel<<<blocks, 256, 0, stream>>>(logits, cls_pred, det_idx, det_flag,
                                          num_det, out);
}

// Round 2
// 95.200 us; speedup vs baseline: 1.3609x; 1.3609x over previous
//
#include <hip/hip_runtime.h>

#pragma clang fp contract(off)

#define NP 410881  // 641*641

// ---------------------------------------------------------------------------
// Kernel 1: per-slot tables from transformer_class_probs (128 x 134).
// One wave per 8 rows; shuffle-reduce (max, first-index) over 133 cols.
// ---------------------------------------------------------------------------
__global__ __launch_bounds__(1024) void slot_kernel(
    const float* __restrict__ probs, float* __restrict__ cls_pred,
    int* __restrict__ det_idx, unsigned long long* __restrict__ det_mask,
    int* __restrict__ num_det) {
  __shared__ float s_val[128];
  __shared__ int s_arg[128];
  __shared__ int s_tot0;
  int tid = threadIdx.x;
  int wv = tid >> 6, lane = tid & 63;

  float bvv[8];
  int bii[8];
#pragma unroll
  for (int k = 0; k < 8; ++k) {  // preload: 24 outstanding loads per lane
    int r = wv * 8 + k;
    const float* row = probs + r * 134;
    float v0 = row[lane];
    float v1 = row[lane + 64];
    float v2 = (lane < 5) ? row[lane + 128] : -1.0f;
    float bv = v0;
    int bi = lane;
    if (v1 > bv) { bv = v1; bi = lane + 64; }
    if (v2 > bv) { bv = v2; bi = lane + 128; }
    bvv[k] = bv; bii[k] = bi;
  }
#pragma unroll
  for (int k = 0; k < 8; ++k) {
    float bv = bvv[k];
    int bi = bii[k];
#pragma unroll
    for (int off = 32; off; off >>= 1) {  // (max, first-idx) butterfly
      float ov = __shfl_xor(bv, off);
      int oi = __shfl_xor(bi, off);
      if (ov > bv || (ov == bv && oi < bi)) { bv = ov; bi = oi; }
    }
    if (lane == 0) { s_val[wv * 8 + k] = bv; s_arg[wv * 8 + k] = bi; }
  }
  __syncthreads();

  bool flag = false;
  unsigned long long b = 0;
  if (tid < 128) flag = s_val[tid] >= 0.7f;
  if (wv < 2) b = __ballot(flag);  // wave-uniform branch
  if (tid < 128 && lane == 0) {
    det_mask[wv] = b;
    if (wv == 0) s_tot0 = __popcll(b);
  }
  __syncthreads();
  if (tid < 128) {
    int incl = __popcll(b & ((1ull << lane) - 1)) + (flag ? 1 : 0) +
               (wv ? s_tot0 : 0);
    det_idx[tid] = incl - 1;  // cumsum(det)-1
    cls_pred[tid] = (float)s_arg[tid];
    if (tid == 127) *num_det = incl;
  }
}

// ---------------------------------------------------------------------------
// Kernel 2: lanes = pixels. Block of 128 threads covers a 16x16 output
// region; each lane owns a 1x2 x-strip inside one bilinear cell. 5x5 input
// texel neighborhood staged in LDS [cell][132] (pad -> bank spread).
// Channel loop is serial per lane: running max/argmax + sum(exp(v)).
// ---------------------------------------------------------------------------
__global__ __launch_bounds__(128) void post_kernel(
    const float* __restrict__ logits, const float* __restrict__ ws_cls,
    const int* __restrict__ ws_didx,
    const unsigned long long* __restrict__ ws_mask,
    const int* __restrict__ ws_ndet, float* __restrict__ out) {
#pragma clang fp contract(off)
  __shared__ float tex[25 * 132];
  __shared__ float s_cls[128];
  __shared__ int s_didx[128];
  int tid = threadIdx.x;
  int X0 = blockIdx.x << 4, Y0 = blockIdx.y << 4;

  // lane -> pixel pair
  int strip = tid & 7, py = tid >> 3;
  int cx = strip >> 1, h = strip & 1;
  int cy = py >> 2;
  int xa = X0 + (cx << 2) + (h << 1);
  int y = Y0 + py;

  int ndet = *ws_ndet;  // uniform
  if (ndet == 0) {      // reference zeroes everything when nothing detected
    if (y < 641) {
      if (xa < 641) {
        int i0 = y * 641 + xa;
        out[i0] = 1.0f; out[NP + i0] = 0.f; out[2 * NP + i0] = 0.f; out[3 * NP + i0] = 0.f;
      }
      if (xa + 1 < 641) {
        int i1 = y * 641 + xa + 1;
        out[i1] = 1.0f; out[NP + i1] = 0.f; out[2 * NP + i1] = 0.f; out[3 * NP + i1] = 0.f;
      }
    }
    return;
  }

  // ---- stage 5x5 texels x 128 ch into LDS (transposed to [cell][132]) ----
  int tX = blockIdx.x << 2, tY = blockIdx.y << 2;  // texel origin
  for (int f = tid; f < 800; f += 128) {           // 800 float4 granules
    int r = f / 160;
    int i = f - r * 160;
    int cc = i >> 5, c4 = i & 31;
    int gy = min(tY + r, 160);
    int gx = min(tX + cc, 160);
    float4 v = *(const float4*)(logits + ((gy * 161 + gx) << 7) + (c4 << 2));
    *(float4*)(tex + (r * 5 + cc) * 132 + (c4 << 2)) = v;
  }
  s_cls[tid] = ws_cls[tid];
  s_didx[tid] = ws_didx[tid];
  __syncthreads();

  const float* p0 = tex + (cy * 5 + cx) * 132;  // a00 @ +0, a01 @ +132
  const float* p1 = p0 + 5 * 132;               // a10, a11
  float wy = 0.25f * (float)(py & 3);
  float iwy = 1.0f - wy;
  float wx0 = 0.5f * (float)h;
  float wx1 = wx0 + 0.25f;
  float iwx0 = 1.0f - wx0, iwx1 = 1.0f - wx1;

  float m0 = -INFINITY, m1 = -INFINITY;  // masked max
  int am0 = 0, am1 = 0;                  // masked argmax (first-index)
  float T0 = 0.f, T1 = 0.f;              // sum exp(v) over detected
  bool dp0 = true, dp1 = true;           // detected_pixel

  if (ndet == 128) {  // fast path: masked == resized
#pragma unroll 4
    for (int c = 0; c < 128; ++c) {
      float a00 = p0[c], a01 = p0[c + 132];
      float a10 = p1[c], a11 = p1[c + 132];
      float r0 = a00 * iwy + a10 * wy;  // same op order as reference
      float r1 = a01 * iwy + a11 * wy;
      float v0 = r0 * iwx0 + r1 * wx0;
      float v1 = r0 * iwx1 + r1 * wx1;
      bool g0 = v0 > m0; m0 = g0 ? v0 : m0; am0 = g0 ? c : am0;
      bool g1 = v1 > m1; m1 = g1 ? v1 : m1; am1 = g1 ? c : am1;
      T0 += __expf(v0);
      T1 += __expf(v1);
    }
  } else {  // general: separate raw max; per-channel detection is uniform
    unsigned long long mlo = ws_mask[0], mhi = ws_mask[1];
    float rm0 = -INFINITY, rm1 = -INFINITY;
#pragma unroll 4
    for (int c = 0; c < 128; ++c) {
      float a00 = p0[c], a01 = p0[c + 132];
      float a10 = p1[c], a11 = p1[c + 132];
      float r0 = a00 * iwy + a10 * wy;
      float r1 = a01 * iwy + a11 * wy;
      float v0 = r0 * iwx0 + r1 * wx0;
      float v1 = r0 * iwx1 + r1 * wx1;
      rm0 = fmaxf(rm0, v0);
      rm1 = fmaxf(rm1, v1);
      unsigned long long bit = (c < 64) ? (mlo >> c) : (mhi >> (c - 64));
      if (bit & 1) {  // scalar branch (wave-uniform)
        bool g0 = v0 > m0; m0 = g0 ? v0 : m0; am0 = g0 ? c : am0;
        bool g1 = v1 > m1; m1 = g1 ? v1 : m1; am1 = g1 ? c : am1;
        T0 += __expf(v0);
        T1 += __expf(v1);
      }
    }
    dp0 = (rm0 == m0);
    dp1 = (rm1 == m1);
  }

  // ---- epilogue: conf > 0.4  <=>  exp(m) > 0.4*T  (T > 0, all v bounded)
  float cg0 = ((__expf(m0) > 0.4f * T0) && dp0) ? 1.0f : 0.0f;
  float cg1 = ((__expf(m1) > 0.4f * T1) && dp1) ? 1.0f : 0.0f;
  float sem0 = s_cls[am0], sem1 = s_cls[am1];
  float mid0 = (float)(s_didx[am0] + 1), mid1 = (float)(s_didx[am1] + 1);
  float th0 = (sem0 < 80.f) ? cg0 : 0.f;
  float st0 = cg0 - th0;
  float th1 = (sem1 < 80.f) ? cg1 : 0.f;
  float st1 = cg1 - th1;

  if (y < 641) {
    if (xa < 641) {
      int i0 = y * 641 + xa;
      out[i0] = mid0; out[NP + i0] = sem0; out[2 * NP + i0] = th0; out[3 * NP + i0] = st0;
    }
    if (xa + 1 < 641) {
      int i1 = y * 641 + xa + 1;
      out[i1] = mid1; out[NP + i1] = sem1; out[2 * NP + i1] = th1; out[3 * NP + i1] = st1;
    }
  }
}

extern "C" void kernel_launch(void* const* d_in, const int* in_sizes, int n_in,
                              void* d_out, int out_size, void* d_ws,
                              size_t ws_size, hipStream_t stream) {
  const float* logits = (const float*)d_in[0];  // (161,161,128) f32
  const float* probs = (const float*)d_in[1];   // (128,134) f32
  float* out = (float*)d_out;

  float* ws_f = (float*)d_ws;
  float* cls_pred = ws_f;                                    // 128 f32
  int* det_idx = (int*)(ws_f + 128);                         // 128 i32
  unsigned long long* det_mask = (unsigned long long*)(ws_f + 256);  // 2 u64
  int* num_det = (int*)(ws_f + 260);                         // 1 i32

  slot_kernel<<<1, 1024, 0, stream>>>(probs, cls_pred, det_idx, det_mask,
                                      num_det);

  dim3 grid(41, 41);
  post_kernel<<<grid, 128, 0, stream>>>(logits, cls_pred, det_idx, det_mask,
                                        num_det, out);
}